// Round 5
// baseline (148.388 us; speedup 1.0000x reference)
//
#include <hip/hip_runtime.h>

#define N 8192
#define D 512

typedef __attribute__((ext_vector_type(8))) short short8;
typedef __attribute__((ext_vector_type(4))) float f32x4;

typedef const __attribute__((address_space(1))) unsigned int* gas_t;
typedef __attribute__((address_space(3))) unsigned int* las_t;

static __device__ __forceinline__ unsigned short f2bf(float f) {
    unsigned u = __float_as_uint(f);
    unsigned r = (u + 0x7FFFu + ((u >> 16) & 1u)) >> 16;
    return (unsigned short)r;
}
static __device__ __forceinline__ float bf2f(unsigned u) {
    return __uint_as_float(u << 16);
}
static __device__ __forceinline__ void gl_lds16(const unsigned short* g, char* l) {
    __builtin_amdgcn_global_load_lds((gas_t)g, (las_t)l, 16, 0, 0);
}
static __device__ __forceinline__ int tri_cum(int r) { return r * (129 - r) / 2; }

// K1: row-normalize embeddings -> bf16 e[N][D]; also pack thetas + init accumulators.
__global__ void knorm(const float* __restrict__ emb, unsigned short* __restrict__ e,
                      const float* __restrict__ th, float4* __restrict__ th4,
                      float* __restrict__ srow, unsigned* __restrict__ jminrow,
                      unsigned* __restrict__ negrow, unsigned* __restrict__ d2mb) {
    int row  = blockIdx.x * 4 + (threadIdx.x >> 6);
    int lane = threadIdx.x & 63;
    const float4* src = (const float4*)(emb + (size_t)row * D);
    float4 v0 = src[lane * 2];
    float4 v1 = src[lane * 2 + 1];
    float ss = v0.x*v0.x + v0.y*v0.y + v0.z*v0.z + v0.w*v0.w
             + v1.x*v1.x + v1.y*v1.y + v1.z*v1.z + v1.w*v1.w;
#pragma unroll
    for (int off = 1; off < 64; off <<= 1) ss += __shfl_xor(ss, off, 64);
    float inv = 1.0f / fmaxf(sqrtf(ss), 1e-12f);
    unsigned short h0 = f2bf(v0.x * inv), h1 = f2bf(v0.y * inv);
    unsigned short h2 = f2bf(v0.z * inv), h3 = f2bf(v0.w * inv);
    unsigned short h4 = f2bf(v1.x * inv), h5 = f2bf(v1.y * inv);
    unsigned short h6 = f2bf(v1.z * inv), h7 = f2bf(v1.w * inv);
    uint4 pk;
    pk.x = (unsigned)h0 | ((unsigned)h1 << 16);
    pk.y = (unsigned)h2 | ((unsigned)h3 << 16);
    pk.z = (unsigned)h4 | ((unsigned)h5 << 16);
    pk.w = (unsigned)h6 | ((unsigned)h7 << 16);
    ((uint4*)(e + (size_t)row * D))[lane] = pk;

    int tid = threadIdx.x;
    if (tid < 4) {
        int i = blockIdx.x * 4 + tid;
        float x = th[3 * i], y = th[3 * i + 1], z = th[3 * i + 2];
        float4 v; v.x = x; v.y = y; v.z = z; v.w = x * x + y * y + z * z;
        th4[i] = v;
        srow[i] = 0.0f;
        jminrow[i] = 0xFFFFFFFFu;
        negrow[i] = 0u;
    }
    if (blockIdx.x == 0 && tid == 0) *d2mb = 0u;
}

// K3: global max of squared pairwise theta distance. Each wave owns 8 rows
// (quad 4w..4w+3 + mirror quad) in registers and scans j once for all 8
// (duplicate j<i pairs are harmless under max). 1024 waves, 134 MB L2 traffic.
__global__ void kd2max(const float4* __restrict__ th4, unsigned* __restrict__ d2mb) {
    int widx = blockIdx.x * 4 + (threadIdx.x >> 6);   // 0..1023
    int lane = threadIdx.x & 63;
    int q0 = widx * 4;
    int m0 = N - 4 - q0;
    float4 a0 = th4[q0], a1 = th4[q0 + 1], a2 = th4[q0 + 2], a3 = th4[q0 + 3];
    float4 b0 = th4[m0], b1 = th4[m0 + 1], b2 = th4[m0 + 2], b3 = th4[m0 + 3];
    float m = 0.0f;
    for (int j = q0 + 1 + lane; j < N; j += 64) {
        float4 tj = th4[j];
        float d;
        d = a0.w + tj.w - 2.0f * (a0.x*tj.x + a0.y*tj.y + a0.z*tj.z); m = fmaxf(m, d);
        d = a1.w + tj.w - 2.0f * (a1.x*tj.x + a1.y*tj.y + a1.z*tj.z); m = fmaxf(m, d);
        d = a2.w + tj.w - 2.0f * (a2.x*tj.x + a2.y*tj.y + a2.z*tj.z); m = fmaxf(m, d);
        d = a3.w + tj.w - 2.0f * (a3.x*tj.x + a3.y*tj.y + a3.z*tj.z); m = fmaxf(m, d);
    }
    for (int j = m0 + 1 + lane; j < N; j += 64) {
        float4 tj = th4[j];
        float d;
        d = b0.w + tj.w - 2.0f * (b0.x*tj.x + b0.y*tj.y + b0.z*tj.z); m = fmaxf(m, d);
        d = b1.w + tj.w - 2.0f * (b1.x*tj.x + b1.y*tj.y + b1.z*tj.z); m = fmaxf(m, d);
        d = b2.w + tj.w - 2.0f * (b2.x*tj.x + b2.y*tj.y + b2.z*tj.z); m = fmaxf(m, d);
        d = b3.w + tj.w - 2.0f * (b3.x*tj.x + b3.y*tj.y + b3.z*tj.z); m = fmaxf(m, d);
    }
#pragma unroll
    for (int off = 1; off < 64; off <<= 1) m = fmaxf(m, __shfl_xor(m, off, 64));
    __shared__ float red[4];
    int w = threadIdx.x >> 6;
    if (lane == 0) red[w] = m;
    __syncthreads();
    if (threadIdx.x == 0) {
        m = fmaxf(fmaxf(red[0], red[1]), fmaxf(red[2], red[3]));
        atomicMax(d2mb, __float_as_uint(m));
    }
}

// K4: symmetric fused GEMM over the upper-triangle tile grid (2080 blocks).
// 128x128 tile/block, 512 threads = 8 waves (2M x 4N, 64x32 per wave, acc 4x2),
// BK=64 double-buffered global_load_lds staging (2-phase), XOR-swizzled source.
// 64 KB LDS -> 2 blocks/CU -> 16 waves/CU (2x round-4 occupancy).
// Fused epilogue scatters masked exp both row-side and (off-diag) column-side.
__global__ __launch_bounds__(512, 4) void kmain(
    const unsigned short* __restrict__ e, const float4* __restrict__ th4,
    const unsigned* __restrict__ d2mb, float* __restrict__ srow,
    unsigned* __restrict__ jminrow, unsigned* __restrict__ negrow) {
    __shared__ __align__(16) char sA0[16384];
    __shared__ __align__(16) char sB0[16384];
    __shared__ __align__(16) char sA1[16384];
    __shared__ __align__(16) char sB1[16384];

    const int tid  = threadIdx.x;
    const int lane = tid & 63;
    const int w    = tid >> 6;        // 0..7
    const int wr   = w >> 2;          // 0..1  (M, 64-row span)
    const int wc   = w & 3;           // 0..3  (N, 32-col span)

    // XCD-aware bijective swizzle: 2080 blocks = 8 XCDs x 260
    const int bid = (int)blockIdx.x;
    const int swz = (bid & 7) * 260 + (bid >> 3);
    int rb = (int)((129.0f - sqrtf(16641.0f - 8.0f * (float)swz)) * 0.5f);
    rb = rb < 0 ? 0 : (rb > 63 ? 63 : rb);
    while (tri_cum(rb + 1) <= swz) rb++;
    while (tri_cum(rb) > swz) rb--;
    const int cb = rb + (swz - tri_cum(rb));
    const bool isdiag = (rb == cb);
    const int r0 = rb * 128, c0 = cb * 128;

    // staging: 16 chunks of 1KB per matrix-buffer; wave w owns chunks 2w, 2w+1.
    // chunk k covers rows 8k..8k+7; lane writes LDS linearly at chunk*1024+lane*16;
    // global source column pre-swizzled so LDS[row][kb] = global(row, kb^((row&7)<<4)).
    const int l8 = lane >> 3, l7 = lane & 7;
    const int srcoff = ((l7 ^ l8) << 3);
    const unsigned short* pA[2];
    const unsigned short* pB[2];
#pragma unroll
    for (int cc = 0; cc < 2; cc++) {
        const int c = w * 2 + cc;
        pA[cc] = e + (size_t)(r0 + 8 * c + l8) * D + srcoff;
        pB[cc] = e + (size_t)(c0 + 8 * c + l8) * D + srcoff;
    }

    const int fr = lane & 15;   // fragment row/col within 16-tile
    const int fq = lane >> 4;   // 0..3

    f32x4 acc[4][2];
#pragma unroll
    for (int mt = 0; mt < 4; mt++)
#pragma unroll
        for (int nt = 0; nt < 2; nt++) acc[mt][nt] = (f32x4){0.f, 0.f, 0.f, 0.f};

    auto stage = [&](char* dA, char* dB, int k0) {
#pragma unroll
        for (int cc = 0; cc < 2; cc++) {
            gl_lds16(pA[cc] + k0, dA + (w * 2 + cc) * 1024);
            gl_lds16(pB[cc] + k0, dB + (w * 2 + cc) * 1024);
        }
    };
    auto compute = [&](const char* cA, const char* cB) {
#pragma unroll
        for (int ks = 0; ks < 2; ++ks) {
            const int kb = ((ks << 6) | (fq << 4)) ^ (l7 << 4);  // swizzled k-byte
            short8 a[4], b[2];
#pragma unroll
            for (int mt = 0; mt < 4; mt++)
                a[mt] = *(const short8*)(cA + (wr * 64 + mt * 16 + fr) * 128 + kb);
#pragma unroll
            for (int nt = 0; nt < 2; nt++)
                b[nt] = *(const short8*)(cB + (wc * 32 + nt * 16 + fr) * 128 + kb);
#pragma unroll
            for (int mt = 0; mt < 4; mt++)
#pragma unroll
                for (int nt = 0; nt < 2; nt++)
                    acc[mt][nt] = __builtin_amdgcn_mfma_f32_16x16x32_bf16(
                        a[mt], b[nt], acc[mt][nt], 0, 0, 0);
        }
    };

    // 2-phase pipeline: STAGE(t+1) issued before compute(t); vmcnt(0)+barrier/step.
    stage(sA0, sB0, 0);
    asm volatile("s_waitcnt vmcnt(0)" ::: "memory");
    __builtin_amdgcn_s_barrier();
#pragma unroll
    for (int kt = 0; kt < 8; kt += 2) {
        stage(sA1, sB1, (kt + 1) * 64);
        compute(sA0, sB0);
        asm volatile("s_waitcnt vmcnt(0)" ::: "memory");
        __builtin_amdgcn_s_barrier();
        if (kt + 2 < 8) stage(sA0, sB0, (kt + 2) * 64);
        compute(sA1, sB1);
        asm volatile("s_waitcnt vmcnt(0)" ::: "memory");
        __builtin_amdgcn_s_barrier();
    }

    // mask thresholds in squared-distance domain
    const float dmax = sqrtf(__uint_as_float(*d2mb)) + 1e-8f;
    const float p2 = 0.0225f * dmax * dmax;   // (0.15*dmax)^2
    const float n2 = 0.1225f * dmax * dmax;   // (0.35*dmax)^2

    const int j0 = c0 + wc * 32 + fr;
    float4 thj[2];
#pragma unroll
    for (int nt = 0; nt < 2; nt++) thj[nt] = th4[j0 + nt * 16];

    float*    lds_rs = (float*)sA0;              // [4][128] row sums (by wc)
    unsigned* lds_rj = (unsigned*)(sA0 + 2048);
    unsigned* lds_rn = (unsigned*)(sA0 + 4096);
    float*    lds_cs = (float*)(sA0 + 6144);     // [2][128] col sums (by wr)
    unsigned* lds_cj = (unsigned*)(sA0 + 7168);
    unsigned* lds_cn = (unsigned*)(sA0 + 8192);

    // column-side accumulators (per lane: columns j0 + nt*16)
    float    csum[2]; unsigned cjm[2], cng[2];
#pragma unroll
    for (int nt = 0; nt < 2; nt++) { csum[nt] = 0.0f; cjm[nt] = 0xFFFFFFFFu; cng[nt] = 0u; }

    // |sim| = |10 * e_i.e_j| <= 10.05 -> the +-30 clamp is a no-op; -30 LSE shift
    // dropped (sum <= 2e8, safe in f32).
    const float K_EXP = 14.4269504089f;  // 10 * log2(e); exp(10x) = 2^(x*K_EXP)

    const int i0 = r0 + wr * 64 + fq * 4;
#pragma unroll
    for (int mt = 0; mt < 4; mt++) {
#pragma unroll
        for (int rr = 0; rr < 4; rr++) {
            const int i = i0 + mt * 16 + rr;
            const float4 ti = th4[i];
            float sv = 0.0f; unsigned jv = 0xFFFFFFFFu, nv = 0u;
#pragma unroll
            for (int nt = 0; nt < 2; nt++) {
                const int j = j0 + nt * 16;
                const float4 tj = thj[nt];
                float dot = ti.x * tj.x + ti.y * tj.y + ti.z * tj.z;
                float d2 = fmaf(-2.0f, dot, ti.w + tj.w);
                bool pos = isdiag ? ((d2 < p2) && (j != i)) : (d2 < p2);
                bool neg = (d2 > n2);
                float c = (pos || neg) ? exp2f(acc[mt][nt][rr] * K_EXP) : 0.0f;
                sv += c;
                if (neg) nv = 1u;
                if (pos) jv = min(jv, (unsigned)j);
                if (!isdiag) {
                    csum[nt] += c;
                    if (neg) cng[nt] = 1u;
                    if (pos) cjm[nt] = min(cjm[nt], (unsigned)i);
                }
            }
            // row-side reduce across the 16 fr-lanes
#pragma unroll
            for (int off = 1; off < 16; off <<= 1) {
                sv += __shfl_xor(sv, off, 64);
                jv = min(jv, (unsigned)__shfl_xor((int)jv, off, 64));
                nv |= (unsigned)__shfl_xor((int)nv, off, 64);
            }
            if (fr == 0) {
                const int rl = wr * 64 + mt * 16 + fq * 4 + rr;
                lds_rs[wc * 128 + rl] = sv;
                lds_rj[wc * 128 + rl] = jv;
                lds_rn[wc * 128 + rl] = nv;
            }
        }
    }

    // column-side reduce across the 4 fq groups (lane^16, lane^32)
    if (!isdiag) {
#pragma unroll
        for (int nt = 0; nt < 2; nt++) {
            float sv = csum[nt]; unsigned jv = cjm[nt], nv = cng[nt];
#pragma unroll
            for (int off = 16; off < 64; off <<= 1) {
                sv += __shfl_xor(sv, off, 64);
                jv = min(jv, (unsigned)__shfl_xor((int)jv, off, 64));
                nv |= (unsigned)__shfl_xor((int)nv, off, 64);
            }
            if (fq == 0) {
                const int cl = wc * 32 + nt * 16 + fr;
                lds_cs[wr * 128 + cl] = sv;
                lds_cj[wr * 128 + cl] = jv;
                lds_cn[wr * 128 + cl] = nv;
            }
        }
    }
    __syncthreads();
    if (tid < 128) {
        float    sv = lds_rs[tid] + lds_rs[128 + tid] + lds_rs[256 + tid] + lds_rs[384 + tid];
        unsigned jv = min(min(lds_rj[tid], lds_rj[128 + tid]),
                          min(lds_rj[256 + tid], lds_rj[384 + tid]));
        unsigned nv = lds_rn[tid] | lds_rn[128 + tid] | lds_rn[256 + tid] | lds_rn[384 + tid];
        atomicAdd(&srow[r0 + tid], sv);
        atomicMin(&jminrow[r0 + tid], jv);
        atomicOr(&negrow[r0 + tid], nv);
        if (!isdiag) {
            float    cv = lds_cs[tid] + lds_cs[128 + tid];
            unsigned cj = min(lds_cj[tid], lds_cj[128 + tid]);
            unsigned cn = lds_cn[tid] | lds_cn[128 + tid];
            atomicAdd(&srow[c0 + tid], cv);
            atomicMin(&jminrow[c0 + tid], cj);
            atomicOr(&negrow[c0 + tid], cn);
        }
    }
}

// K5: per-row finalize: tgt logit = 10 * e_i . e_jmin; per_row = log(s) - tgt.
__global__ void krow(const unsigned short* __restrict__ e, const float* __restrict__ srow,
                     const unsigned* __restrict__ jminrow, const unsigned* __restrict__ negrow,
                     float* __restrict__ pr, float* __restrict__ vf) {
    int row  = blockIdx.x * 4 + (threadIdx.x >> 6);
    int lane = threadIdx.x & 63;
    unsigned jmv = jminrow[row];
    bool valid = (jmv != 0xFFFFFFFFu) && (negrow[row] != 0u);
    float p = 0.0f;
    if (valid) {
        const uint4* a = (const uint4*)(e + (size_t)row * D);
        const uint4* b = (const uint4*)(e + (size_t)jmv * D);
        uint4 va = a[lane], vb = b[lane];
        float dot = 0.0f;
        dot += bf2f(va.x & 0xFFFFu) * bf2f(vb.x & 0xFFFFu);
        dot += bf2f(va.x >> 16)     * bf2f(vb.x >> 16);
        dot += bf2f(va.y & 0xFFFFu) * bf2f(vb.y & 0xFFFFu);
        dot += bf2f(va.y >> 16)     * bf2f(vb.y >> 16);
        dot += bf2f(va.z & 0xFFFFu) * bf2f(vb.z & 0xFFFFu);
        dot += bf2f(va.z >> 16)     * bf2f(vb.z >> 16);
        dot += bf2f(va.w & 0xFFFFu) * bf2f(vb.w & 0xFFFFu);
        dot += bf2f(va.w >> 16)     * bf2f(vb.w >> 16);
#pragma unroll
        for (int off = 1; off < 64; off <<= 1) dot += __shfl_xor(dot, off, 64);
        p = logf(srow[row]) - dot * 10.0f;
    }
    if (lane == 0) { pr[row] = p; vf[row] = valid ? 1.0f : 0.0f; }
}

// K6: deterministic fixed-tree reduction -> scalar loss.
__global__ void kfinal(const float* __restrict__ pr, const float* __restrict__ vf,
                       float* __restrict__ out) {
    __shared__ float ls[1024];
    __shared__ float lc[1024];
    int t = threadIdx.x;
    float sv = 0.0f, cv = 0.0f;
#pragma unroll
    for (int k = 0; k < 8; k++) { sv += pr[t * 8 + k]; cv += vf[t * 8 + k]; }
    ls[t] = sv; lc[t] = cv;
    __syncthreads();
    for (int off = 512; off > 0; off >>= 1) {
        if (t < off) { ls[t] += ls[t + off]; lc[t] += lc[t + off]; }
        __syncthreads();
    }
    if (t == 0) out[0] = (lc[0] > 0.0f) ? (ls[0] / lc[0]) : 0.0f;
}

extern "C" void kernel_launch(void* const* d_in, const int* in_sizes, int n_in,
                              void* d_out, int out_size, void* d_ws, size_t ws_size,
                              hipStream_t stream) {
    const float* emb = (const float*)d_in[0];
    const float* th  = (const float*)d_in[1];
    float* out = (float*)d_out;
    char* ws = (char*)d_ws;

    unsigned short* e    = (unsigned short*)(ws);                 // 8 MB bf16 [N][D]
    float4*   th4        = (float4*)(ws + 8388608);               // 128 KB
    float*    srow       = (float*)(ws + 8519680);                // 32 KB
    unsigned* jminr      = (unsigned*)(ws + 8552448);             // 32 KB
    unsigned* negr       = (unsigned*)(ws + 8585216);             // 32 KB
    float*    pr         = (float*)(ws + 8617984);                // 32 KB
    float*    vf         = (float*)(ws + 8650752);                // 32 KB
    unsigned* d2mb       = (unsigned*)(ws + 8683520);             // 4 B

    knorm<<<N / 4, 256, 0, stream>>>(emb, e, th, th4, srow, jminr, negr, d2mb);
    kd2max<<<256, 256, 0, stream>>>(th4, d2mb);
    kmain<<<2080, 512, 0, stream>>>(e, th4, d2mb, srow, jminr, negr);
    krow<<<N / 4, 256, 0, stream>>>(e, srow, jminr, negr, pr, vf);
    kfinal<<<1, 1024, 0, stream>>>(pr, vf, out);
}

// Round 6
// 147.855 us; speedup vs baseline: 1.0036x; 1.0036x over previous
//
#include <hip/hip_runtime.h>

#define N 8192
#define D 512

typedef __attribute__((ext_vector_type(8))) short short8;
typedef __attribute__((ext_vector_type(4))) float f32x4;

typedef const __attribute__((address_space(1))) unsigned int* gas_t;
typedef __attribute__((address_space(3))) unsigned int* las_t;

static __device__ __forceinline__ unsigned short f2bf(float f) {
    unsigned u = __float_as_uint(f);
    unsigned r = (u + 0x7FFFu + ((u >> 16) & 1u)) >> 16;
    return (unsigned short)r;
}
static __device__ __forceinline__ float bf2f(unsigned u) {
    return __uint_as_float(u << 16);
}
static __device__ __forceinline__ void gl_lds16(const unsigned short* g, char* l) {
    __builtin_amdgcn_global_load_lds((gas_t)g, (las_t)l, 16, 0, 0);
}
// triangle cumulative for 32x32 tile grid: row r owns (32-r) tiles
static __device__ __forceinline__ int tc32(int r) { return r * (65 - r) / 2; }

// K1: row-normalize embeddings -> bf16 e[N][D]; also pack thetas + init accumulators.
__global__ void knorm(const float* __restrict__ emb, unsigned short* __restrict__ e,
                      const float* __restrict__ th, float4* __restrict__ th4,
                      float* __restrict__ srow, unsigned* __restrict__ jminrow,
                      unsigned* __restrict__ negrow, unsigned* __restrict__ d2mb) {
    int row  = blockIdx.x * 4 + (threadIdx.x >> 6);
    int lane = threadIdx.x & 63;
    const float4* src = (const float4*)(emb + (size_t)row * D);
    float4 v0 = src[lane * 2];
    float4 v1 = src[lane * 2 + 1];
    float ss = v0.x*v0.x + v0.y*v0.y + v0.z*v0.z + v0.w*v0.w
             + v1.x*v1.x + v1.y*v1.y + v1.z*v1.z + v1.w*v1.w;
#pragma unroll
    for (int off = 1; off < 64; off <<= 1) ss += __shfl_xor(ss, off, 64);
    float inv = 1.0f / fmaxf(sqrtf(ss), 1e-12f);
    unsigned short h0 = f2bf(v0.x * inv), h1 = f2bf(v0.y * inv);
    unsigned short h2 = f2bf(v0.z * inv), h3 = f2bf(v0.w * inv);
    unsigned short h4 = f2bf(v1.x * inv), h5 = f2bf(v1.y * inv);
    unsigned short h6 = f2bf(v1.z * inv), h7 = f2bf(v1.w * inv);
    uint4 pk;
    pk.x = (unsigned)h0 | ((unsigned)h1 << 16);
    pk.y = (unsigned)h2 | ((unsigned)h3 << 16);
    pk.z = (unsigned)h4 | ((unsigned)h5 << 16);
    pk.w = (unsigned)h6 | ((unsigned)h7 << 16);
    ((uint4*)(e + (size_t)row * D))[lane] = pk;

    int tid = threadIdx.x;
    if (tid < 4) {
        int i = blockIdx.x * 4 + tid;
        float x = th[3 * i], y = th[3 * i + 1], z = th[3 * i + 2];
        float4 v; v.x = x; v.y = y; v.z = z; v.w = x * x + y * y + z * z;
        th4[i] = v;
        srow[i] = 0.0f;
        jminrow[i] = 0xFFFFFFFFu;
        negrow[i] = 0u;
    }
    if (blockIdx.x == 0 && tid == 0) *d2mb = 0u;
}

// K3: global max of squared pairwise theta distance. Each wave owns 8 rows
// (quad + mirror quad) in registers and scans j once for all 8.
__global__ void kd2max(const float4* __restrict__ th4, unsigned* __restrict__ d2mb) {
    int widx = blockIdx.x * 4 + (threadIdx.x >> 6);   // 0..1023
    int lane = threadIdx.x & 63;
    int q0 = widx * 4;
    int m0 = N - 4 - q0;
    float4 a0 = th4[q0], a1 = th4[q0 + 1], a2 = th4[q0 + 2], a3 = th4[q0 + 3];
    float4 b0 = th4[m0], b1 = th4[m0 + 1], b2 = th4[m0 + 2], b3 = th4[m0 + 3];
    float m = 0.0f;
    for (int j = q0 + 1 + lane; j < N; j += 64) {
        float4 tj = th4[j];
        float d;
        d = a0.w + tj.w - 2.0f * (a0.x*tj.x + a0.y*tj.y + a0.z*tj.z); m = fmaxf(m, d);
        d = a1.w + tj.w - 2.0f * (a1.x*tj.x + a1.y*tj.y + a1.z*tj.z); m = fmaxf(m, d);
        d = a2.w + tj.w - 2.0f * (a2.x*tj.x + a2.y*tj.y + a2.z*tj.z); m = fmaxf(m, d);
        d = a3.w + tj.w - 2.0f * (a3.x*tj.x + a3.y*tj.y + a3.z*tj.z); m = fmaxf(m, d);
    }
    for (int j = m0 + 1 + lane; j < N; j += 64) {
        float4 tj = th4[j];
        float d;
        d = b0.w + tj.w - 2.0f * (b0.x*tj.x + b0.y*tj.y + b0.z*tj.z); m = fmaxf(m, d);
        d = b1.w + tj.w - 2.0f * (b1.x*tj.x + b1.y*tj.y + b1.z*tj.z); m = fmaxf(m, d);
        d = b2.w + tj.w - 2.0f * (b2.x*tj.x + b2.y*tj.y + b2.z*tj.z); m = fmaxf(m, d);
        d = b3.w + tj.w - 2.0f * (b3.x*tj.x + b3.y*tj.y + b3.z*tj.z); m = fmaxf(m, d);
    }
#pragma unroll
    for (int off = 1; off < 64; off <<= 1) m = fmaxf(m, __shfl_xor(m, off, 64));
    __shared__ float red[4];
    int w = threadIdx.x >> 6;
    if (lane == 0) red[w] = m;
    __syncthreads();
    if (threadIdx.x == 0) {
        m = fmaxf(fmaxf(red[0], red[1]), fmaxf(red[2], red[3]));
        atomicMax(d2mb, __float_as_uint(m));
    }
}

// K4: symmetric fused GEMM, 256x256 tile/block over the 32x32 upper-triangle grid
// (528 blocks), 512 threads = 8 waves (2M x 4N, wave tile 128x64, acc 8x4).
// BK=64, two 64KB LDS tile-buffers, COUNTED-vmcnt pipeline: stage(kt+2) is issued
// right after the compute-done barrier; the per-step wait is vmcnt(8) (stage kt+1
// stays in flight) — never a vmcnt(0) drain until the final step.
__global__ __launch_bounds__(512, 2) void kmain(
    const unsigned short* __restrict__ e, const float4* __restrict__ th4,
    const unsigned* __restrict__ d2mb, float* __restrict__ srow,
    unsigned* __restrict__ jminrow, unsigned* __restrict__ negrow) {
    __shared__ __align__(16) char smem[131072];   // 2 buffers x (A 32K + B 32K)

    const int tid  = threadIdx.x;
    const int lane = tid & 63;
    const int w    = tid >> 6;        // 0..7
    const int wr   = w >> 2;          // 0..1  (M, 128-row half)
    const int wc   = w & 3;           // 0..3  (N, 64-col slice)

    // XCD-aware bijective swizzle: 528 blocks = 8 XCDs x 66
    const int bid = (int)blockIdx.x;
    const int swz = (bid & 7) * 66 + (bid >> 3);
    int rb = (int)((65.0f - sqrtf(4225.0f - 8.0f * (float)swz)) * 0.5f);
    rb = rb < 0 ? 0 : (rb > 31 ? 31 : rb);
    while (tc32(rb + 1) <= swz) rb++;
    while (tc32(rb) > swz) rb--;
    const int cb = rb + (swz - tc32(rb));
    const bool isdiag = (rb == cb);
    const int r0 = rb * 256, c0 = cb * 256;

    // staging: per buffer, A = 32 chunks of 1KB (8 rows x 128B each), B likewise.
    // wave w owns chunks 4w..4w+3. lane l covers row l>>3, 16B-block l&7 of its
    // chunk; global source column pre-swizzled so LDS[row][blk] = g(row, blk^(row&7)).
    const int l8 = lane >> 3, l7 = lane & 7;
    const int srcoff = ((l7 ^ l8) << 3);   // elements within the 64-elem K-slab
    const unsigned short* pA[4];
    const unsigned short* pB[4];
#pragma unroll
    for (int cc = 0; cc < 4; cc++) {
        const int c = w * 4 + cc;
        pA[cc] = e + (size_t)(r0 + 8 * c + l8) * D + srcoff;
        pB[cc] = e + (size_t)(c0 + 8 * c + l8) * D + srcoff;
    }

    const int fr = lane & 15;   // fragment row/col within 16-tile
    const int fq = lane >> 4;   // 0..3

    f32x4 acc[8][4];
#pragma unroll
    for (int mt = 0; mt < 8; mt++)
#pragma unroll
        for (int nt = 0; nt < 4; nt++) acc[mt][nt] = (f32x4){0.f, 0.f, 0.f, 0.f};

    auto stage = [&](int kt, int buf) {
        char* dA = smem + buf * 65536;
        char* dB = dA + 32768;
        const int k0 = kt * 64;
#pragma unroll
        for (int cc = 0; cc < 4; cc++) gl_lds16(pA[cc] + k0, dA + (w * 4 + cc) * 1024);
#pragma unroll
        for (int cc = 0; cc < 4; cc++) gl_lds16(pB[cc] + k0, dB + (w * 4 + cc) * 1024);
    };
    auto compute = [&](int buf) {
        const char* cA = smem + buf * 65536;
        const char* cB = cA + 32768;
#pragma unroll
        for (int ks = 0; ks < 2; ++ks) {
            const int kb = (((ks << 2) | fq) ^ (fr & 7)) << 4;  // swizzled k-byte
            short8 a[8], b[4];
#pragma unroll
            for (int mt = 0; mt < 8; mt++)
                a[mt] = *(const short8*)(cA + (wr * 128 + mt * 16 + fr) * 128 + kb);
#pragma unroll
            for (int nt = 0; nt < 4; nt++)
                b[nt] = *(const short8*)(cB + (wc * 64 + nt * 16 + fr) * 128 + kb);
#pragma unroll
            for (int mt = 0; mt < 8; mt++)
#pragma unroll
                for (int nt = 0; nt < 4; nt++)
                    acc[mt][nt] = __builtin_amdgcn_mfma_f32_16x16x32_bf16(
                        a[mt], b[nt], acc[mt][nt], 0, 0, 0);
        }
    };

#define KSTEP(KT, WAITN)                                              \
    asm volatile("s_waitcnt vmcnt(" #WAITN ")" ::: "memory");         \
    __builtin_amdgcn_s_barrier();                                     \
    __builtin_amdgcn_sched_barrier(0);                                \
    compute((KT) & 1);                                                \
    __builtin_amdgcn_sched_barrier(0);                                \
    __builtin_amdgcn_s_barrier();                                     \
    __builtin_amdgcn_sched_barrier(0);                                \
    if ((KT) + 2 < 8) stage((KT) + 2, (KT) & 1);

    // prologue: two tiles in flight
    stage(0, 0);
    stage(1, 1);
    KSTEP(0, 8)
    KSTEP(1, 8)
    KSTEP(2, 8)
    KSTEP(3, 8)
    KSTEP(4, 8)
    KSTEP(5, 8)
    KSTEP(6, 8)
    KSTEP(7, 0)
#undef KSTEP

    // ---- fused epilogue ----
    const float dmax = sqrtf(__uint_as_float(*d2mb)) + 1e-8f;
    const float p2 = 0.0225f * dmax * dmax;   // (0.15*dmax)^2
    const float n2 = 0.1225f * dmax * dmax;   // (0.35*dmax)^2

    float4*   th_r = (float4*)smem;               // [256] row thetas
    float4*   th_c = (float4*)(smem + 4096);      // [256] col thetas
    float*    rs   = (float*)(smem + 8192);       // [4][256] row sums by wc
    unsigned* rj   = (unsigned*)(smem + 12288);
    unsigned* rn   = (unsigned*)(smem + 16384);
    float*    cs   = (float*)(smem + 20480);      // [2][256] col sums by wr
    unsigned* cj   = (unsigned*)(smem + 22528);
    unsigned* cn   = (unsigned*)(smem + 24576);

    // all staging landed (vmcnt(0) at step 7) and all compute done (last barrier)
    if (tid < 256) th_r[tid] = th4[r0 + tid];
    else           th_c[tid - 256] = th4[c0 + tid - 256];
    __syncthreads();

    const int jbase = wc * 64 + fr;
    float4 thj[4];
#pragma unroll
    for (int nt = 0; nt < 4; nt++) thj[nt] = th_c[jbase + nt * 16];

    float    csum[4]; unsigned cjm[4], cng[4];
#pragma unroll
    for (int nt = 0; nt < 4; nt++) { csum[nt] = 0.0f; cjm[nt] = 0xFFFFFFFFu; cng[nt] = 0u; }

    // |sim| = |10 * e_i.e_j| <= ~10.05 -> +-30 clamp is a no-op; LSE shift dropped.
    const float K_EXP = 14.4269504089f;  // 10 * log2(e)

    const int ilb = wr * 128 + fq * 4;
#pragma unroll
    for (int mt = 0; mt < 8; mt++) {
#pragma unroll
        for (int rr = 0; rr < 4; rr++) {
            const int il = ilb + mt * 16 + rr;
            const int i  = r0 + il;
            const float4 ti = th_r[il];
            float sv = 0.0f; unsigned jv = 0xFFFFFFFFu, nv = 0u;
#pragma unroll
            for (int nt = 0; nt < 4; nt++) {
                const int j = c0 + jbase + nt * 16;
                const float4 tj = thj[nt];
                float dot = ti.x * tj.x + ti.y * tj.y + ti.z * tj.z;
                float d2 = fmaf(-2.0f, dot, ti.w + tj.w);
                bool pos = isdiag ? ((d2 < p2) && (j != i)) : (d2 < p2);
                bool neg = (d2 > n2);
                float c = (pos || neg) ? exp2f(acc[mt][nt][rr] * K_EXP) : 0.0f;
                sv += c;
                if (neg) nv = 1u;
                if (pos) jv = min(jv, (unsigned)j);
                if (!isdiag) {
                    csum[nt] += c;
                    if (neg) cng[nt] = 1u;
                    if (pos) cjm[nt] = min(cjm[nt], (unsigned)i);
                }
            }
            // row-side reduce across the 16 fr-lanes
#pragma unroll
            for (int off = 1; off < 16; off <<= 1) {
                sv += __shfl_xor(sv, off, 64);
                jv = min(jv, (unsigned)__shfl_xor((int)jv, off, 64));
                nv |= (unsigned)__shfl_xor((int)nv, off, 64);
            }
            if (fr == 0) {
                rs[wc * 256 + il] = sv;
                rj[wc * 256 + il] = jv;
                rn[wc * 256 + il] = nv;
            }
        }
    }

    // column-side reduce across the 4 fq groups (lane^16, lane^32)
    if (!isdiag) {
#pragma unroll
        for (int nt = 0; nt < 4; nt++) {
            float sv = csum[nt]; unsigned jv = cjm[nt], nv = cng[nt];
#pragma unroll
            for (int off = 16; off < 64; off <<= 1) {
                sv += __shfl_xor(sv, off, 64);
                jv = min(jv, (unsigned)__shfl_xor((int)jv, off, 64));
                nv |= (unsigned)__shfl_xor((int)nv, off, 64);
            }
            if (fq == 0) {
                const int jl = jbase + nt * 16;
                cs[wr * 256 + jl] = sv;
                cj[wr * 256 + jl] = jv;
                cn[wr * 256 + jl] = nv;
            }
        }
    }
    __syncthreads();
    if (tid < 256) {
        float    sv = rs[tid] + rs[256 + tid] + rs[512 + tid] + rs[768 + tid];
        unsigned jv = min(min(rj[tid], rj[256 + tid]), min(rj[512 + tid], rj[768 + tid]));
        unsigned nv = rn[tid] | rn[256 + tid] | rn[512 + tid] | rn[768 + tid];
        atomicAdd(&srow[r0 + tid], sv);
        atomicMin(&jminrow[r0 + tid], jv);
        atomicOr(&negrow[r0 + tid], nv);
    } else if (!isdiag) {
        const int t2 = tid - 256;
        float    cv = cs[t2] + cs[256 + t2];
        unsigned jj = min(cj[t2], cj[256 + t2]);
        unsigned nn = cn[t2] | cn[256 + t2];
        atomicAdd(&srow[c0 + t2], cv);
        atomicMin(&jminrow[c0 + t2], jj);
        atomicOr(&negrow[c0 + t2], nn);
    }
}

// K5: per-row finalize: tgt logit = 10 * e_i . e_jmin; per_row = log(s) - tgt.
__global__ void krow(const unsigned short* __restrict__ e, const float* __restrict__ srow,
                     const unsigned* __restrict__ jminrow, const unsigned* __restrict__ negrow,
                     float* __restrict__ pr, float* __restrict__ vf) {
    int row  = blockIdx.x * 4 + (threadIdx.x >> 6);
    int lane = threadIdx.x & 63;
    unsigned jmv = jminrow[row];
    bool valid = (jmv != 0xFFFFFFFFu) && (negrow[row] != 0u);
    float p = 0.0f;
    if (valid) {
        const uint4* a = (const uint4*)(e + (size_t)row * D);
        const uint4* b = (const uint4*)(e + (size_t)jmv * D);
        uint4 va = a[lane], vb = b[lane];
        float dot = 0.0f;
        dot += bf2f(va.x & 0xFFFFu) * bf2f(vb.x & 0xFFFFu);
        dot += bf2f(va.x >> 16)     * bf2f(vb.x >> 16);
        dot += bf2f(va.y & 0xFFFFu) * bf2f(vb.y & 0xFFFFu);
        dot += bf2f(va.y >> 16)     * bf2f(vb.y >> 16);
        dot += bf2f(va.z & 0xFFFFu) * bf2f(vb.z & 0xFFFFu);
        dot += bf2f(va.z >> 16)     * bf2f(vb.z >> 16);
        dot += bf2f(va.w & 0xFFFFu) * bf2f(vb.w & 0xFFFFu);
        dot += bf2f(va.w >> 16)     * bf2f(vb.w >> 16);
#pragma unroll
        for (int off = 1; off < 64; off <<= 1) dot += __shfl_xor(dot, off, 64);
        p = logf(srow[row]) - dot * 10.0f;
    }
    if (lane == 0) { pr[row] = p; vf[row] = valid ? 1.0f : 0.0f; }
}

// K6: deterministic fixed-tree reduction -> scalar loss.
__global__ void kfinal(const float* __restrict__ pr, const float* __restrict__ vf,
                       float* __restrict__ out) {
    __shared__ float ls[1024];
    __shared__ float lc[1024];
    int t = threadIdx.x;
    float sv = 0.0f, cv = 0.0f;
#pragma unroll
    for (int k = 0; k < 8; k++) { sv += pr[t * 8 + k]; cv += vf[t * 8 + k]; }
    ls[t] = sv; lc[t] = cv;
    __syncthreads();
    for (int off = 512; off > 0; off >>= 1) {
        if (t < off) { ls[t] += ls[t + off]; lc[t] += lc[t + off]; }
        __syncthreads();
    }
    if (t == 0) out[0] = (lc[0] > 0.0f) ? (ls[0] / lc[0]) : 0.0f;
}

extern "C" void kernel_launch(void* const* d_in, const int* in_sizes, int n_in,
                              void* d_out, int out_size, void* d_ws, size_t ws_size,
                              hipStream_t stream) {
    const float* emb = (const float*)d_in[0];
    const float* th  = (const float*)d_in[1];
    float* out = (float*)d_out;
    char* ws = (char*)d_ws;

    unsigned short* e    = (unsigned short*)(ws);                 // 8 MB bf16 [N][D]
    float4*   th4        = (float4*)(ws + 8388608);               // 128 KB
    float*    srow       = (float*)(ws + 8519680);                // 32 KB
    unsigned* jminr      = (unsigned*)(ws + 8552448);             // 32 KB
    unsigned* negr       = (unsigned*)(ws + 8585216);             // 32 KB
    float*    pr         = (float*)(ws + 8617984);                // 32 KB
    float*    vf         = (float*)(ws + 8650752);                // 32 KB
    unsigned* d2mb       = (unsigned*)(ws + 8683520);             // 4 B

    knorm<<<N / 4, 256, 0, stream>>>(emb, e, th, th4, srow, jminr, negr, d2mb);
    kd2max<<<256, 256, 0, stream>>>(th4, d2mb);
    kmain<<<528, 512, 0, stream>>>(e, th4, d2mb, srow, jminr, negr);
    krow<<<N / 4, 256, 0, stream>>>(e, srow, jminr, negr, pr, vf);
    kfinal<<<1, 1024, 0, stream>>>(pr, vf, out);
}

// Round 7
// 145.343 us; speedup vs baseline: 1.0210x; 1.0173x over previous
//
#include <hip/hip_runtime.h>

#define N 8192
#define D 512

typedef __attribute__((ext_vector_type(8))) short short8;
typedef __attribute__((ext_vector_type(4))) float f32x4;

typedef const __attribute__((address_space(1))) unsigned int* gas_t;
typedef __attribute__((address_space(3))) unsigned int* las_t;

static __device__ __forceinline__ unsigned short f2bf(float f) {
    unsigned u = __float_as_uint(f);
    unsigned r = (u + 0x7FFFu + ((u >> 16) & 1u)) >> 16;
    return (unsigned short)r;
}
static __device__ __forceinline__ float bf2f(unsigned u) {
    return __uint_as_float(u << 16);
}
static __device__ __forceinline__ void gl_lds16(const unsigned short* g, char* l) {
    __builtin_amdgcn_global_load_lds((gas_t)g, (las_t)l, 16, 0, 0);
}
// triangle cumulative for 32x32 tile grid: row r owns (32-r) tiles
static __device__ __forceinline__ int tc32(int r) { return r * (65 - r) / 2; }

// K1: row-normalize embeddings -> bf16 e[N][D]; also pack thetas + init accumulators.
__global__ void knorm(const float* __restrict__ emb, unsigned short* __restrict__ e,
                      const float* __restrict__ th, float4* __restrict__ th4,
                      float* __restrict__ srow, unsigned* __restrict__ jminrow,
                      unsigned* __restrict__ negrow, unsigned* __restrict__ d2mb) {
    int row  = blockIdx.x * 4 + (threadIdx.x >> 6);
    int lane = threadIdx.x & 63;
    const float4* src = (const float4*)(emb + (size_t)row * D);
    float4 v0 = src[lane * 2];
    float4 v1 = src[lane * 2 + 1];
    float ss = v0.x*v0.x + v0.y*v0.y + v0.z*v0.z + v0.w*v0.w
             + v1.x*v1.x + v1.y*v1.y + v1.z*v1.z + v1.w*v1.w;
#pragma unroll
    for (int off = 1; off < 64; off <<= 1) ss += __shfl_xor(ss, off, 64);
    float inv = 1.0f / fmaxf(sqrtf(ss), 1e-12f);
    unsigned short h0 = f2bf(v0.x * inv), h1 = f2bf(v0.y * inv);
    unsigned short h2 = f2bf(v0.z * inv), h3 = f2bf(v0.w * inv);
    unsigned short h4 = f2bf(v1.x * inv), h5 = f2bf(v1.y * inv);
    unsigned short h6 = f2bf(v1.z * inv), h7 = f2bf(v1.w * inv);
    uint4 pk;
    pk.x = (unsigned)h0 | ((unsigned)h1 << 16);
    pk.y = (unsigned)h2 | ((unsigned)h3 << 16);
    pk.z = (unsigned)h4 | ((unsigned)h5 << 16);
    pk.w = (unsigned)h6 | ((unsigned)h7 << 16);
    ((uint4*)(e + (size_t)row * D))[lane] = pk;

    int tid = threadIdx.x;
    if (tid < 4) {
        int i = blockIdx.x * 4 + tid;
        float x = th[3 * i], y = th[3 * i + 1], z = th[3 * i + 2];
        float4 v; v.x = x; v.y = y; v.z = z; v.w = x * x + y * y + z * z;
        th4[i] = v;
        srow[i] = 0.0f;
        jminrow[i] = 0xFFFFFFFFu;
        negrow[i] = 0u;
    }
    if (blockIdx.x == 0 && tid == 0) *d2mb = 0u;
}

// K3: global max of squared pairwise theta distance. Each wave owns 8 rows
// (quad + mirror quad) in registers and scans j once for all 8.
__global__ void kd2max(const float4* __restrict__ th4, unsigned* __restrict__ d2mb) {
    int widx = blockIdx.x * 4 + (threadIdx.x >> 6);   // 0..1023
    int lane = threadIdx.x & 63;
    int q0 = widx * 4;
    int m0 = N - 4 - q0;
    float4 a0 = th4[q0], a1 = th4[q0 + 1], a2 = th4[q0 + 2], a3 = th4[q0 + 3];
    float4 b0 = th4[m0], b1 = th4[m0 + 1], b2 = th4[m0 + 2], b3 = th4[m0 + 3];
    float m = 0.0f;
    for (int j = q0 + 1 + lane; j < N; j += 64) {
        float4 tj = th4[j];
        float d;
        d = a0.w + tj.w - 2.0f * (a0.x*tj.x + a0.y*tj.y + a0.z*tj.z); m = fmaxf(m, d);
        d = a1.w + tj.w - 2.0f * (a1.x*tj.x + a1.y*tj.y + a1.z*tj.z); m = fmaxf(m, d);
        d = a2.w + tj.w - 2.0f * (a2.x*tj.x + a2.y*tj.y + a2.z*tj.z); m = fmaxf(m, d);
        d = a3.w + tj.w - 2.0f * (a3.x*tj.x + a3.y*tj.y + a3.z*tj.z); m = fmaxf(m, d);
    }
    for (int j = m0 + 1 + lane; j < N; j += 64) {
        float4 tj = th4[j];
        float d;
        d = b0.w + tj.w - 2.0f * (b0.x*tj.x + b0.y*tj.y + b0.z*tj.z); m = fmaxf(m, d);
        d = b1.w + tj.w - 2.0f * (b1.x*tj.x + b1.y*tj.y + b1.z*tj.z); m = fmaxf(m, d);
        d = b2.w + tj.w - 2.0f * (b2.x*tj.x + b2.y*tj.y + b2.z*tj.z); m = fmaxf(m, d);
        d = b3.w + tj.w - 2.0f * (b3.x*tj.x + b3.y*tj.y + b3.z*tj.z); m = fmaxf(m, d);
    }
#pragma unroll
    for (int off = 1; off < 64; off <<= 1) m = fmaxf(m, __shfl_xor(m, off, 64));
    __shared__ float red[4];
    int w = threadIdx.x >> 6;
    if (lane == 0) red[w] = m;
    __syncthreads();
    if (threadIdx.x == 0) {
        m = fmaxf(fmaxf(red[0], red[1]), fmaxf(red[2], red[3]));
        atomicMax(d2mb, __float_as_uint(m));
    }
}

// K4: symmetric fused GEMM, 256x256 tile/block over the 32x32 upper-triangle grid
// (528 blocks), 512 threads = 8 waves (2M x 4N, wave tile 128x64, acc 8x4).
// BK=32, THREE 32KB LDS tile-buffers rotating: stage(kt+2) is issued BEFORE
// compute(kt) -> 2 full K-steps of prefetch lookahead; per-step wait is a counted
// vmcnt(4) (next two stages stay in flight); one barrier per step.
__global__ __launch_bounds__(512, 2) void kmain(
    const unsigned short* __restrict__ e, const float4* __restrict__ th4,
    const unsigned* __restrict__ d2mb, float* __restrict__ srow,
    unsigned* __restrict__ jminrow, unsigned* __restrict__ negrow) {
    __shared__ __align__(16) char smem[98304];   // 3 buffers x (A 16K + B 16K)

    const int tid  = threadIdx.x;
    const int lane = tid & 63;
    const int w    = tid >> 6;        // 0..7
    const int wr   = w >> 2;          // 0..1  (M, 128-row half)
    const int wc   = w & 3;           // 0..3  (N, 64-col slice)

    // XCD-aware bijective swizzle: 528 blocks = 8 XCDs x 66
    const int bid = (int)blockIdx.x;
    const int swz = (bid & 7) * 66 + (bid >> 3);
    int rb = (int)((65.0f - sqrtf(4225.0f - 8.0f * (float)swz)) * 0.5f);
    rb = rb < 0 ? 0 : (rb > 31 ? 31 : rb);
    while (tc32(rb + 1) <= swz) rb++;
    while (tc32(rb) > swz) rb--;
    const int cb = rb + (swz - tc32(rb));
    const bool isdiag = (rb == cb);
    const int r0 = rb * 256, c0 = cb * 256;

    // staging geometry (BK=32): per buffer, A = 16 chunks of 1KB (16 rows x 64B),
    // B likewise. wave w owns A chunks 2w,2w+1 and B chunks 2w,2w+1 (4 loads/thr).
    // lane l: row = l>>2 within chunk, 16B-slot = l&3; LDS dest linear at
    // chunk*1024 + l*16; global source slot pre-swizzled so that
    // LDS[row][s] = global(row, s ^ ((row>>1)&3)).
    const int lrow = lane >> 2;
    const int srcoff = (((lane & 3) ^ ((lane >> 3) & 3)) << 3);  // elements
    const unsigned short* pA[2];
    const unsigned short* pB[2];
#pragma unroll
    for (int cc = 0; cc < 2; cc++) {
        const int ch = w * 2 + cc;
        pA[cc] = e + (size_t)(r0 + 16 * ch + lrow) * D + srcoff;
        pB[cc] = e + (size_t)(c0 + 16 * ch + lrow) * D + srcoff;
    }

    const int fr = lane & 15;   // fragment row/col within 16-tile
    const int fq = lane >> 4;   // 0..3
    // read-side swizzled 16B-slot offset; (row>>1)&3 == (fr>>1)&3 for all our rows
    const int kbsw = (fq ^ ((fr >> 1) & 3)) << 4;

    f32x4 acc[8][4];
#pragma unroll
    for (int mt = 0; mt < 8; mt++)
#pragma unroll
        for (int nt = 0; nt < 4; nt++) acc[mt][nt] = (f32x4){0.f, 0.f, 0.f, 0.f};

    auto stage = [&](int kt, int buf) {
        char* dA = smem + buf * 32768;
        char* dB = dA + 16384;
        const int k0 = kt * 32;
#pragma unroll
        for (int cc = 0; cc < 2; cc++) gl_lds16(pA[cc] + k0, dA + (w * 2 + cc) * 1024);
#pragma unroll
        for (int cc = 0; cc < 2; cc++) gl_lds16(pB[cc] + k0, dB + (w * 2 + cc) * 1024);
    };
    auto compute = [&](int buf) {
        const char* cA = smem + buf * 32768;
        const char* cB = cA + 16384;
        short8 a[8], b[4];
#pragma unroll
        for (int mt = 0; mt < 8; mt++)
            a[mt] = *(const short8*)(cA + (wr * 128 + mt * 16 + fr) * 64 + kbsw);
#pragma unroll
        for (int nt = 0; nt < 4; nt++)
            b[nt] = *(const short8*)(cB + (wc * 64 + nt * 16 + fr) * 64 + kbsw);
#pragma unroll
        for (int mt = 0; mt < 8; mt++)
#pragma unroll
            for (int nt = 0; nt < 4; nt++)
                acc[mt][nt] = __builtin_amdgcn_mfma_f32_16x16x32_bf16(
                    a[mt], b[nt], acc[mt][nt], 0, 0, 0);
    };

    // 3-buffer rotation, 16 K-steps. Step kt: wait(stage kt landed) -> barrier ->
    // issue stage(kt+2) into buf (kt+2)%3 (its readers kt-1 finished pre-barrier)
    // -> compute(kt). Counted waits: vmcnt(4) except final step vmcnt(0).
#define KSTEP(KT, WAITN, DOSTAGE)                                     \
    asm volatile("s_waitcnt vmcnt(" #WAITN ")" ::: "memory");         \
    __builtin_amdgcn_s_barrier();                                     \
    __builtin_amdgcn_sched_barrier(0);                                \
    if (DOSTAGE) stage((KT) + 2, ((KT) + 2) % 3);                     \
    __builtin_amdgcn_sched_barrier(0);                                \
    compute((KT) % 3);

    stage(0, 0);
    stage(1, 1);
    KSTEP(0, 4, 1)  KSTEP(1, 4, 1)  KSTEP(2, 4, 1)  KSTEP(3, 4, 1)
    KSTEP(4, 4, 1)  KSTEP(5, 4, 1)  KSTEP(6, 4, 1)  KSTEP(7, 4, 1)
    KSTEP(8, 4, 1)  KSTEP(9, 4, 1)  KSTEP(10, 4, 1) KSTEP(11, 4, 1)
    KSTEP(12, 4, 1) KSTEP(13, 4, 1) KSTEP(14, 4, 0) KSTEP(15, 0, 0)
#undef KSTEP
    __syncthreads();   // all waves done computing before LDS reuse below

    // ---- fused epilogue ----
    const float dmax = sqrtf(__uint_as_float(*d2mb)) + 1e-8f;
    const float p2 = 0.0225f * dmax * dmax;   // (0.15*dmax)^2
    const float n2 = 0.1225f * dmax * dmax;   // (0.35*dmax)^2

    float4*   th_r = (float4*)smem;               // [256] row thetas
    float4*   th_c = (float4*)(smem + 4096);      // [256] col thetas
    float*    rs   = (float*)(smem + 8192);       // [4][256] row sums by wc
    unsigned* rj   = (unsigned*)(smem + 12288);
    unsigned* rn   = (unsigned*)(smem + 16384);
    float*    cs   = (float*)(smem + 20480);      // [2][256] col sums by wr
    unsigned* cj   = (unsigned*)(smem + 22528);
    unsigned* cn   = (unsigned*)(smem + 24576);

    if (tid < 256) th_r[tid] = th4[r0 + tid];
    else           th_c[tid - 256] = th4[c0 + tid - 256];
    __syncthreads();

    const int jbase = wc * 64 + fr;
    float4 thj[4];
#pragma unroll
    for (int nt = 0; nt < 4; nt++) thj[nt] = th_c[jbase + nt * 16];

    float    csum[4]; unsigned cjm[4], cng[4];
#pragma unroll
    for (int nt = 0; nt < 4; nt++) { csum[nt] = 0.0f; cjm[nt] = 0xFFFFFFFFu; cng[nt] = 0u; }

    // |sim| = |10 * e_i.e_j| <= ~10.05 -> +-30 clamp is a no-op; LSE shift dropped.
    const float K_EXP = 14.4269504089f;  // 10 * log2(e)

    const int ilb = wr * 128 + fq * 4;
#pragma unroll
    for (int mt = 0; mt < 8; mt++) {
#pragma unroll
        for (int rr = 0; rr < 4; rr++) {
            const int il = ilb + mt * 16 + rr;
            const int i  = r0 + il;
            const float4 ti = th_r[il];
            float sv = 0.0f; unsigned jv = 0xFFFFFFFFu, nv = 0u;
#pragma unroll
            for (int nt = 0; nt < 4; nt++) {
                const int j = c0 + jbase + nt * 16;
                const float4 tj = thj[nt];
                float dot = ti.x * tj.x + ti.y * tj.y + ti.z * tj.z;
                float d2 = fmaf(-2.0f, dot, ti.w + tj.w);
                bool pos = isdiag ? ((d2 < p2) && (j != i)) : (d2 < p2);
                bool neg = (d2 > n2);
                float c = (pos || neg) ? exp2f(acc[mt][nt][rr] * K_EXP) : 0.0f;
                sv += c;
                if (neg) nv = 1u;
                if (pos) jv = min(jv, (unsigned)j);
                if (!isdiag) {
                    csum[nt] += c;
                    if (neg) cng[nt] = 1u;
                    if (pos) cjm[nt] = min(cjm[nt], (unsigned)i);
                }
            }
            // row-side reduce across the 16 fr-lanes
#pragma unroll
            for (int off = 1; off < 16; off <<= 1) {
                sv += __shfl_xor(sv, off, 64);
                jv = min(jv, (unsigned)__shfl_xor((int)jv, off, 64));
                nv |= (unsigned)__shfl_xor((int)nv, off, 64);
            }
            if (fr == 0) {
                rs[wc * 256 + il] = sv;
                rj[wc * 256 + il] = jv;
                rn[wc * 256 + il] = nv;
            }
        }
    }

    // column-side reduce across the 4 fq groups (lane^16, lane^32)
    if (!isdiag) {
#pragma unroll
        for (int nt = 0; nt < 4; nt++) {
            float sv = csum[nt]; unsigned jv = cjm[nt], nv = cng[nt];
#pragma unroll
            for (int off = 16; off < 64; off <<= 1) {
                sv += __shfl_xor(sv, off, 64);
                jv = min(jv, (unsigned)__shfl_xor((int)jv, off, 64));
                nv |= (unsigned)__shfl_xor((int)nv, off, 64);
            }
            if (fq == 0) {
                const int jl = jbase + nt * 16;
                cs[wr * 256 + jl] = sv;
                cj[wr * 256 + jl] = jv;
                cn[wr * 256 + jl] = nv;
            }
        }
    }
    __syncthreads();
    if (tid < 256) {
        float    sv = rs[tid] + rs[256 + tid] + rs[512 + tid] + rs[768 + tid];
        unsigned jv = min(min(rj[tid], rj[256 + tid]), min(rj[512 + tid], rj[768 + tid]));
        unsigned nv = rn[tid] | rn[256 + tid] | rn[512 + tid] | rn[768 + tid];
        atomicAdd(&srow[r0 + tid], sv);
        atomicMin(&jminrow[r0 + tid], jv);
        atomicOr(&negrow[r0 + tid], nv);
    } else if (!isdiag) {
        const int t2 = tid - 256;
        float    cv = cs[t2] + cs[256 + t2];
        unsigned jj = min(cj[t2], cj[256 + t2]);
        unsigned nn = cn[t2] | cn[256 + t2];
        atomicAdd(&srow[c0 + t2], cv);
        atomicMin(&jminrow[c0 + t2], jj);
        atomicOr(&negrow[c0 + t2], nn);
    }
}

// K5: per-row finalize: tgt logit = 10 * e_i . e_jmin; per_row = log(s) - tgt.
__global__ void krow(const unsigned short* __restrict__ e, const float* __restrict__ srow,
                     const unsigned* __restrict__ jminrow, const unsigned* __restrict__ negrow,
                     float* __restrict__ pr, float* __restrict__ vf) {
    int row  = blockIdx.x * 4 + (threadIdx.x >> 6);
    int lane = threadIdx.x & 63;
    unsigned jmv = jminrow[row];
    bool valid = (jmv != 0xFFFFFFFFu) && (negrow[row] != 0u);
    float p = 0.0f;
    if (valid) {
        const uint4* a = (const uint4*)(e + (size_t)row * D);
        const uint4* b = (const uint4*)(e + (size_t)jmv * D);
        uint4 va = a[lane], vb = b[lane];
        float dot = 0.0f;
        dot += bf2f(va.x & 0xFFFFu) * bf2f(vb.x & 0xFFFFu);
        dot += bf2f(va.x >> 16)     * bf2f(vb.x >> 16);
        dot += bf2f(va.y & 0xFFFFu) * bf2f(vb.y & 0xFFFFu);
        dot += bf2f(va.y >> 16)     * bf2f(vb.y >> 16);
        dot += bf2f(va.z & 0xFFFFu) * bf2f(vb.z & 0xFFFFu);
        dot += bf2f(va.z >> 16)     * bf2f(vb.z >> 16);
        dot += bf2f(va.w & 0xFFFFu) * bf2f(vb.w & 0xFFFFu);
        dot += bf2f(va.w >> 16)     * bf2f(vb.w >> 16);
#pragma unroll
        for (int off = 1; off < 64; off <<= 1) dot += __shfl_xor(dot, off, 64);
        p = logf(srow[row]) - dot * 10.0f;
    }
    if (lane == 0) { pr[row] = p; vf[row] = valid ? 1.0f : 0.0f; }
}

// K6: deterministic fixed-tree reduction -> scalar loss.
__global__ void kfinal(const float* __restrict__ pr, const float* __restrict__ vf,
                       float* __restrict__ out) {
    __shared__ float ls[1024];
    __shared__ float lc[1024];
    int t = threadIdx.x;
    float sv = 0.0f, cv = 0.0f;
#pragma unroll
    for (int k = 0; k < 8; k++) { sv += pr[t * 8 + k]; cv += vf[t * 8 + k]; }
    ls[t] = sv; lc[t] = cv;
    __syncthreads();
    for (int off = 512; off > 0; off >>= 1) {
        if (t < off) { ls[t] += ls[t + off]; lc[t] += lc[t + off]; }
        __syncthreads();
    }
    if (t == 0) out[0] = (lc[0] > 0.0f) ? (ls[0] / lc[0]) : 0.0f;
}

extern "C" void kernel_launch(void* const* d_in, const int* in_sizes, int n_in,
                              void* d_out, int out_size, void* d_ws, size_t ws_size,
                              hipStream_t stream) {
    const float* emb = (const float*)d_in[0];
    const float* th  = (const float*)d_in[1];
    float* out = (float*)d_out;
    char* ws = (char*)d_ws;

    unsigned short* e    = (unsigned short*)(ws);                 // 8 MB bf16 [N][D]
    float4*   th4        = (float4*)(ws + 8388608);               // 128 KB
    float*    srow       = (float*)(ws + 8519680);                // 32 KB
    unsigned* jminr      = (unsigned*)(ws + 8552448);             // 32 KB
    unsigned* negr       = (unsigned*)(ws + 8585216);             // 32 KB
    float*    pr         = (float*)(ws + 8617984);                // 32 KB
    float*    vf         = (float*)(ws + 8650752);                // 32 KB
    unsigned* d2mb       = (unsigned*)(ws + 8683520);             // 4 B

    knorm<<<N / 4, 256, 0, stream>>>(emb, e, th, th4, srow, jminr, negr, d2mb);
    kd2max<<<256, 256, 0, stream>>>(th4, d2mb);
    kmain<<<528, 512, 0, stream>>>(e, th4, d2mb, srow, jminr, negr);
    krow<<<N / 4, 256, 0, stream>>>(e, srow, jminr, negr, pr, vf);
    kfinal<<<1, 1024, 0, stream>>>(pr, vf, out);
}

// Round 8
// 145.075 us; speedup vs baseline: 1.0228x; 1.0018x over previous
//
#include <hip/hip_runtime.h>

#define N 8192
#define D 512

typedef __attribute__((ext_vector_type(8))) short short8;
typedef __attribute__((ext_vector_type(4))) float f32x4;

typedef const __attribute__((address_space(1))) unsigned int* gas_t;
typedef __attribute__((address_space(3))) unsigned int* las_t;

static __device__ __forceinline__ unsigned short f2bf(float f) {
    unsigned u = __float_as_uint(f);
    unsigned r = (u + 0x7FFFu + ((u >> 16) & 1u)) >> 16;
    return (unsigned short)r;
}
static __device__ __forceinline__ float bf2f(unsigned u) {
    return __uint_as_float(u << 16);
}
static __device__ __forceinline__ void gl_lds16(const unsigned short* g, char* l) {
    __builtin_amdgcn_global_load_lds((gas_t)g, (las_t)l, 16, 0, 0);
}
static __device__ __forceinline__ int tc32(int r) { return r * (65 - r) / 2; }

// K1: row-normalize embeddings -> bf16 e[N][D], PRE-SCALED by sqrt(10*log2(e))
// so the GEMM accumulator is directly the exp2 argument. Also packs thetas.
__global__ void knorm(const float* __restrict__ emb, unsigned short* __restrict__ e,
                      const float* __restrict__ th, float4* __restrict__ th4,
                      float* __restrict__ srow, unsigned* __restrict__ jminrow,
                      unsigned* __restrict__ negrow, unsigned* __restrict__ d2mb) {
    int row  = blockIdx.x * 4 + (threadIdx.x >> 6);
    int lane = threadIdx.x & 63;
    const float4* src = (const float4*)(emb + (size_t)row * D);
    float4 v0 = src[lane * 2];
    float4 v1 = src[lane * 2 + 1];
    float ss = v0.x*v0.x + v0.y*v0.y + v0.z*v0.z + v0.w*v0.w
             + v1.x*v1.x + v1.y*v1.y + v1.z*v1.z + v1.w*v1.w;
#pragma unroll
    for (int off = 1; off < 64; off <<= 1) ss += __shfl_xor(ss, off, 64);
    // 3.7982826^2 = 14.42695 = 10*log2(e): acc becomes exp2 argument directly
    float inv = 3.7982826f / fmaxf(sqrtf(ss), 1e-12f);
    unsigned short h0 = f2bf(v0.x * inv), h1 = f2bf(v0.y * inv);
    unsigned short h2 = f2bf(v0.z * inv), h3 = f2bf(v0.w * inv);
    unsigned short h4 = f2bf(v1.x * inv), h5 = f2bf(v1.y * inv);
    unsigned short h6 = f2bf(v1.z * inv), h7 = f2bf(v1.w * inv);
    uint4 pk;
    pk.x = (unsigned)h0 | ((unsigned)h1 << 16);
    pk.y = (unsigned)h2 | ((unsigned)h3 << 16);
    pk.z = (unsigned)h4 | ((unsigned)h5 << 16);
    pk.w = (unsigned)h6 | ((unsigned)h7 << 16);
    ((uint4*)(e + (size_t)row * D))[lane] = pk;

    int tid = threadIdx.x;
    if (tid < 4) {
        int i = blockIdx.x * 4 + tid;
        float x = th[3 * i], y = th[3 * i + 1], z = th[3 * i + 2];
        float4 v; v.x = x; v.y = y; v.z = z; v.w = x * x + y * y + z * z;
        th4[i] = v;
        srow[i] = 0.0f;
        jminrow[i] = 0xFFFFFFFFu;
        negrow[i] = 0u;
    }
    if (blockIdx.x == 0 && tid == 0) *d2mb = 0u;
}

// K3: global max of squared pairwise theta distance (8 rows per wave in regs).
__global__ void kd2max(const float4* __restrict__ th4, unsigned* __restrict__ d2mb) {
    int widx = blockIdx.x * 4 + (threadIdx.x >> 6);
    int lane = threadIdx.x & 63;
    int q0 = widx * 4;
    int m0 = N - 4 - q0;
    float4 a0 = th4[q0], a1 = th4[q0 + 1], a2 = th4[q0 + 2], a3 = th4[q0 + 3];
    float4 b0 = th4[m0], b1 = th4[m0 + 1], b2 = th4[m0 + 2], b3 = th4[m0 + 3];
    float m = 0.0f;
    for (int j = q0 + 1 + lane; j < N; j += 64) {
        float4 tj = th4[j];
        float d;
        d = a0.w + tj.w - 2.0f * (a0.x*tj.x + a0.y*tj.y + a0.z*tj.z); m = fmaxf(m, d);
        d = a1.w + tj.w - 2.0f * (a1.x*tj.x + a1.y*tj.y + a1.z*tj.z); m = fmaxf(m, d);
        d = a2.w + tj.w - 2.0f * (a2.x*tj.x + a2.y*tj.y + a2.z*tj.z); m = fmaxf(m, d);
        d = a3.w + tj.w - 2.0f * (a3.x*tj.x + a3.y*tj.y + a3.z*tj.z); m = fmaxf(m, d);
    }
    for (int j = m0 + 1 + lane; j < N; j += 64) {
        float4 tj = th4[j];
        float d;
        d = b0.w + tj.w - 2.0f * (b0.x*tj.x + b0.y*tj.y + b0.z*tj.z); m = fmaxf(m, d);
        d = b1.w + tj.w - 2.0f * (b1.x*tj.x + b1.y*tj.y + b1.z*tj.z); m = fmaxf(m, d);
        d = b2.w + tj.w - 2.0f * (b2.x*tj.x + b2.y*tj.y + b2.z*tj.z); m = fmaxf(m, d);
        d = b3.w + tj.w - 2.0f * (b3.x*tj.x + b3.y*tj.y + b3.z*tj.z); m = fmaxf(m, d);
    }
#pragma unroll
    for (int off = 1; off < 64; off <<= 1) m = fmaxf(m, __shfl_xor(m, off, 64));
    __shared__ float red[4];
    int w = threadIdx.x >> 6;
    if (lane == 0) red[w] = m;
    __syncthreads();
    if (threadIdx.x == 0) {
        m = fmaxf(fmaxf(red[0], red[1]), fmaxf(red[2], red[3]));
        atomicMax(d2mb, __float_as_uint(m));
    }
}

// K4: symmetric fused GEMM, 256x256 tile, 8-phase deep-pipelined K-loop.
// Units: A m-half / B n-half = 16 KB = 2 gl_lds/thread. 8 phases per 2 K-tiles:
// each phase {ds-read subtile | stage 1 unit | barrier | lgkm0 | setprio+16 MFMA
// | counted vmcnt | barrier}. Waits vmcnt(10/8) derived from the stage ring;
// units land ~6 phases before use. LDS 128 KB (2 parities x (A 32K + B 32K)).
__global__ __launch_bounds__(512, 2) void kmain(
    const unsigned short* __restrict__ e, const float4* __restrict__ th4,
    const unsigned* __restrict__ d2mb, float* __restrict__ srow,
    unsigned* __restrict__ jminrow, unsigned* __restrict__ negrow) {
    __shared__ __align__(16) char smem[131072];

    const int tid  = threadIdx.x;
    const int lane = tid & 63;
    const int w    = tid >> 6;
    const int wr   = w >> 2;          // 0..1 (M 128-half)
    const int wc   = w & 3;           // 0..3 (N 64-slice)

    const int bid = (int)blockIdx.x;
    const int swz = (bid & 7) * 66 + (bid >> 3);
    int rb = (int)((65.0f - sqrtf(4225.0f - 8.0f * (float)swz)) * 0.5f);
    rb = rb < 0 ? 0 : (rb > 31 ? 31 : rb);
    while (tc32(rb + 1) <= swz) rb++;
    while (tc32(rb) > swz) rb--;
    const int cb = rb + (swz - tc32(rb));
    const bool isdiag = (rb == cb);
    const int r0 = rb * 256, c0 = cb * 256;

    // staging source pointers. soff: pre-swizzled global slot so that
    // LDS[row][slot] = global(row, slot ^ (row&7)) with linear LDS dest.
    const int soff = (((tid & 7) ^ ((tid >> 3) & 7)) << 3);
    const unsigned short* pa[2][2];   // [mhalf][part]
    const unsigned short* pb[2][2];   // [nhalf][part]
#pragma unroll
    for (int mh = 0; mh < 2; mh++)
#pragma unroll
        for (int pt = 0; pt < 2; pt++) {
            pa[mh][pt] = e + (size_t)(r0 + mh * 64 + pt * 128 + (tid >> 3)) * D + soff;
            pb[mh][pt] = e + (size_t)(c0 + pt * 128 + ((tid >> 8) & 1) * 64 + mh * 32
                                      + ((tid >> 3) & 31)) * D + soff;
        }

    const int fr = lane & 15;
    const int fq = lane >> 4;
    const int aoff0 = wr * 8192 + fr * 128 + ((fq ^ (fr & 7)) << 4);
    const int aoff1 = aoff0 ^ 64;
    const int boff0 = wc * 4096 + fr * 128 + ((fq ^ (fr & 7)) << 4);
    const int boff1 = boff0 ^ 64;

    short8 av[4][2];
    short8 bv[2][2][2];
    f32x4 acc[8][4];
#pragma unroll
    for (int mt = 0; mt < 8; mt++)
#pragma unroll
        for (int nt = 0; nt < 4; nt++) acc[mt][nt] = (f32x4){0.f, 0.f, 0.f, 0.f};

#define STAGE_A(T, MH) \
    gl_lds16(pa[MH][0] + (T) * 64, smem + (((T) & 1) * 32768 + (MH) * 16384) + tid * 16); \
    gl_lds16(pa[MH][1] + (T) * 64, smem + (((T) & 1) * 32768 + (MH) * 16384 + 8192) + tid * 16);
#define STAGE_B(T, NH) \
    gl_lds16(pb[NH][0] + (T) * 64, smem + 65536 + (((T) & 1) * 32768 + (NH) * 16384) + tid * 16); \
    gl_lds16(pb[NH][1] + (T) * 64, smem + 65536 + (((T) & 1) * 32768 + (NH) * 16384 + 8192) + tid * 16);
#define RD_A(PAR, MH) \
    _Pragma("unroll") \
    for (int mt = 0; mt < 4; mt++) { \
        av[mt][0] = *(const short8*)(smem + (PAR) * 32768 + (MH) * 16384 + aoff0 + mt * 2048); \
        av[mt][1] = *(const short8*)(smem + (PAR) * 32768 + (MH) * 16384 + aoff1 + mt * 2048); \
    }
#define RD_B(PAR, NH) \
    _Pragma("unroll") \
    for (int ntl = 0; ntl < 2; ntl++) { \
        bv[NH][ntl][0] = *(const short8*)(smem + 65536 + (PAR) * 32768 + (NH) * 16384 + boff0 + ntl * 2048); \
        bv[NH][ntl][1] = *(const short8*)(smem + 65536 + (PAR) * 32768 + (NH) * 16384 + boff1 + ntl * 2048); \
    }
#define MFMA_Q(MH, NH) \
    _Pragma("unroll") \
    for (int mt = 0; mt < 4; mt++) \
    _Pragma("unroll") \
    for (int ntl = 0; ntl < 2; ntl++) { \
        acc[(MH)*4+mt][(NH)*2+ntl] = __builtin_amdgcn_mfma_f32_16x16x32_bf16( \
            av[mt][0], bv[NH][ntl][0], acc[(MH)*4+mt][(NH)*2+ntl], 0, 0, 0); \
        acc[(MH)*4+mt][(NH)*2+ntl] = __builtin_amdgcn_mfma_f32_16x16x32_bf16( \
            av[mt][1], bv[NH][ntl][1], acc[(MH)*4+mt][(NH)*2+ntl], 0, 0, 0); \
    }
#define VM(NN) asm volatile("s_waitcnt vmcnt(" #NN ")" ::: "memory");
#define BAR __builtin_amdgcn_s_barrier();
#define PH_BODY(MH, NH) \
    __builtin_amdgcn_sched_barrier(0); \
    __builtin_amdgcn_s_barrier(); \
    asm volatile("s_waitcnt lgkmcnt(0)" ::: "memory"); \
    __builtin_amdgcn_sched_barrier(0); \
    __builtin_amdgcn_s_setprio(1); \
    MFMA_Q(MH, NH) \
    __builtin_amdgcn_s_setprio(0); \
    __builtin_amdgcn_sched_barrier(0);

// one iteration = K-tiles T (parity 0) and T+1 (parity 1)
#define ITER(T, SE, W3S, W5S, W7S, W8S) \
    /*ph1*/ RD_A(0, 0) RD_B(0, 0) STAGE_A((T) + 1, 1) PH_BODY(0, 0) BAR \
    /*ph2*/ RD_B(0, 1) if (SE) { STAGE_B((T) + 2, 0) } PH_BODY(0, 1) W3S BAR \
    /*ph3*/ RD_A(0, 1) if (SE) { STAGE_B((T) + 2, 1) } PH_BODY(1, 1) BAR \
    /*ph4*/ if (SE) { STAGE_A((T) + 2, 0) } PH_BODY(1, 0) W5S BAR \
    /*ph5*/ RD_A(1, 0) RD_B(1, 0) if (SE) { STAGE_A((T) + 2, 1) } PH_BODY(0, 0) BAR \
    /*ph6*/ RD_B(1, 1) if (SE) { STAGE_B((T) + 3, 0) } PH_BODY(0, 1) W7S BAR \
    /*ph7*/ RD_A(1, 1) if (SE) { STAGE_B((T) + 3, 1) } PH_BODY(1, 1) BAR \
    /*ph8*/ if (SE) { STAGE_A((T) + 3, 0) } PH_BODY(1, 0) W8S BAR

    // prologue: stage ring prefix in canonical queue order (7 units)
    STAGE_B(0, 0) STAGE_B(0, 1) STAGE_A(0, 0) STAGE_A(0, 1)
    STAGE_B(1, 0) STAGE_B(1, 1) STAGE_A(1, 0)
    __builtin_amdgcn_sched_barrier(0);
    VM(8)
    BAR

    ITER(0, 1, VM(10), VM(8), VM(10), VM(8))
    ITER(2, 1, VM(10), VM(8), VM(10), VM(8))
    ITER(4, 1, VM(10), VM(8), VM(10), VM(8))
    ITER(6, 0, VM(8),  VM(2), VM(0),       )

#undef ITER
#undef PH_BODY
#undef BAR
#undef VM
#undef MFMA_Q
#undef RD_B
#undef RD_A
#undef STAGE_B
#undef STAGE_A

    __syncthreads();   // LDS reuse below

    // ---- fused epilogue (acc is the exp2 argument directly) ----
    const float dmax = sqrtf(__uint_as_float(*d2mb)) + 1e-8f;
    const float p2 = 0.0225f * dmax * dmax;
    const float n2 = 0.1225f * dmax * dmax;

    float4*   th_r = (float4*)smem;
    float4*   th_c = (float4*)(smem + 4096);
    float*    rs   = (float*)(smem + 8192);
    unsigned* rj   = (unsigned*)(smem + 12288);
    unsigned* rn   = (unsigned*)(smem + 16384);
    float*    cs   = (float*)(smem + 20480);
    unsigned* cj   = (unsigned*)(smem + 22528);
    unsigned* cn   = (unsigned*)(smem + 24576);

    if (tid < 256) th_r[tid] = th4[r0 + tid];
    else           th_c[tid - 256] = th4[c0 + tid - 256];
    __syncthreads();

    const int jbase = wc * 64 + fr;
    float4 thj[4];
#pragma unroll
    for (int nt = 0; nt < 4; nt++) thj[nt] = th_c[jbase + nt * 16];

    float    csum[4]; unsigned cjm[4], cng[4];
#pragma unroll
    for (int nt = 0; nt < 4; nt++) { csum[nt] = 0.0f; cjm[nt] = 0xFFFFFFFFu; cng[nt] = 0u; }

    const int ilb = wr * 128 + fq * 4;
#pragma unroll
    for (int mt = 0; mt < 8; mt++) {
#pragma unroll
        for (int rr = 0; rr < 4; rr++) {
            const int il = ilb + mt * 16 + rr;
            const int i  = r0 + il;
            const float4 ti = th_r[il];
            float sv = 0.0f; unsigned jv = 0xFFFFFFFFu, nv = 0u;
#pragma unroll
            for (int nt = 0; nt < 4; nt++) {
                const int j = c0 + jbase + nt * 16;
                const float4 tj = thj[nt];
                float dot = ti.x * tj.x + ti.y * tj.y + ti.z * tj.z;
                float d2 = fmaf(-2.0f, dot, ti.w + tj.w);
                bool pos = isdiag ? ((d2 < p2) && (j != i)) : (d2 < p2);
                bool neg = (d2 > n2);
                float c = (pos || neg) ? exp2f(acc[mt][nt][rr]) : 0.0f;
                sv += c;
                if (neg) nv = 1u;
                if (pos) jv = min(jv, (unsigned)j);
                if (!isdiag) {
                    csum[nt] += c;
                    if (neg) cng[nt] = 1u;
                    if (pos) cjm[nt] = min(cjm[nt], (unsigned)i);
                }
            }
#pragma unroll
            for (int off = 1; off < 16; off <<= 1) {
                sv += __shfl_xor(sv, off, 64);
                jv = min(jv, (unsigned)__shfl_xor((int)jv, off, 64));
                nv |= (unsigned)__shfl_xor((int)nv, off, 64);
            }
            if (fr == 0) {
                rs[wc * 256 + il] = sv;
                rj[wc * 256 + il] = jv;
                rn[wc * 256 + il] = nv;
            }
        }
    }

    if (!isdiag) {
#pragma unroll
        for (int nt = 0; nt < 4; nt++) {
            float sv = csum[nt]; unsigned jv = cjm[nt], nv = cng[nt];
#pragma unroll
            for (int off = 16; off < 64; off <<= 1) {
                sv += __shfl_xor(sv, off, 64);
                jv = min(jv, (unsigned)__shfl_xor((int)jv, off, 64));
                nv |= (unsigned)__shfl_xor((int)nv, off, 64);
            }
            if (fq == 0) {
                const int jl = jbase + nt * 16;
                cs[wr * 256 + jl] = sv;
                cj[wr * 256 + jl] = jv;
                cn[wr * 256 + jl] = nv;
            }
        }
    }
    __syncthreads();
    if (tid < 256) {
        float    sv = rs[tid] + rs[256 + tid] + rs[512 + tid] + rs[768 + tid];
        unsigned jv = min(min(rj[tid], rj[256 + tid]), min(rj[512 + tid], rj[768 + tid]));
        unsigned nv = rn[tid] | rn[256 + tid] | rn[512 + tid] | rn[768 + tid];
        atomicAdd(&srow[r0 + tid], sv);
        atomicMin(&jminrow[r0 + tid], jv);
        atomicOr(&negrow[r0 + tid], nv);
    } else if (!isdiag) {
        const int t2 = tid - 256;
        float    cv = cs[t2] + cs[256 + t2];
        unsigned jj = min(cj[t2], cj[256 + t2]);
        unsigned nn = cn[t2] | cn[256 + t2];
        atomicAdd(&srow[c0 + t2], cv);
        atomicMin(&jminrow[c0 + t2], jj);
        atomicOr(&negrow[c0 + t2], nn);
    }
}

// K5: per-row finalize. e is pre-scaled: sim = dot_scaled * ln2.
__global__ void krow(const unsigned short* __restrict__ e, const float* __restrict__ srow,
                     const unsigned* __restrict__ jminrow, const unsigned* __restrict__ negrow,
                     float* __restrict__ pr, float* __restrict__ vf) {
    int row  = blockIdx.x * 4 + (threadIdx.x >> 6);
    int lane = threadIdx.x & 63;
    unsigned jmv = jminrow[row];
    bool valid = (jmv != 0xFFFFFFFFu) && (negrow[row] != 0u);
    float p = 0.0f;
    if (valid) {
        const uint4* a = (const uint4*)(e + (size_t)row * D);
        const uint4* b = (const uint4*)(e + (size_t)jmv * D);
        uint4 va = a[lane], vb = b[lane];
        float dot = 0.0f;
        dot += bf2f(va.x & 0xFFFFu) * bf2f(vb.x & 0xFFFFu);
        dot += bf2f(va.x >> 16)     * bf2f(vb.x >> 16);
        dot += bf2f(va.y & 0xFFFFu) * bf2f(vb.y & 0xFFFFu);
        dot += bf2f(va.y >> 16)     * bf2f(vb.y >> 16);
        dot += bf2f(va.z & 0xFFFFu) * bf2f(vb.z & 0xFFFFu);
        dot += bf2f(va.z >> 16)     * bf2f(vb.z >> 16);
        dot += bf2f(va.w & 0xFFFFu) * bf2f(vb.w & 0xFFFFu);
        dot += bf2f(va.w >> 16)     * bf2f(vb.w >> 16);
#pragma unroll
        for (int off = 1; off < 64; off <<= 1) dot += __shfl_xor(dot, off, 64);
        p = logf(srow[row]) - dot * 0.69314718f;
    }
    if (lane == 0) { pr[row] = p; vf[row] = valid ? 1.0f : 0.0f; }
}

// K6: deterministic fixed-tree reduction -> scalar loss.
__global__ void kfinal(const float* __restrict__ pr, const float* __restrict__ vf,
                       float* __restrict__ out) {
    __shared__ float ls[1024];
    __shared__ float lc[1024];
    int t = threadIdx.x;
    float sv = 0.0f, cv = 0.0f;
#pragma unroll
    for (int k = 0; k < 8; k++) { sv += pr[t * 8 + k]; cv += vf[t * 8 + k]; }
    ls[t] = sv; lc[t] = cv;
    __syncthreads();
    for (int off = 512; off > 0; off >>= 1) {
        if (t < off) { ls[t] += ls[t + off]; lc[t] += lc[t + off]; }
        __syncthreads();
    }
    if (t == 0) out[0] = (lc[0] > 0.0f) ? (ls[0] / lc[0]) : 0.0f;
}

extern "C" void kernel_launch(void* const* d_in, const int* in_sizes, int n_in,
                              void* d_out, int out_size, void* d_ws, size_t ws_size,
                              hipStream_t stream) {
    const float* emb = (const float*)d_in[0];
    const float* th  = (const float*)d_in[1];
    float* out = (float*)d_out;
    char* ws = (char*)d_ws;

    unsigned short* e    = (unsigned short*)(ws);
    float4*   th4        = (float4*)(ws + 8388608);
    float*    srow       = (float*)(ws + 8519680);
    unsigned* jminr      = (unsigned*)(ws + 8552448);
    unsigned* negr       = (unsigned*)(ws + 8585216);
    float*    pr         = (float*)(ws + 8617984);
    float*    vf         = (float*)(ws + 8650752);
    unsigned* d2mb       = (unsigned*)(ws + 8683520);

    knorm<<<N / 4, 256, 0, stream>>>(emb, e, th, th4, srow, jminr, negr, d2mb);
    kd2max<<<256, 256, 0, stream>>>(th4, d2mb);
    kmain<<<528, 512, 0, stream>>>(e, th4, d2mb, srow, jminr, negr);
    krow<<<N / 4, 256, 0, stream>>>(e, srow, jminr, negr, pr, vf);
    kfinal<<<1, 1024, 0, stream>>>(pr, vf, out);
}